// Round 4
// baseline (1765.743 us; speedup 1.0000x reference)
//
#include <hip/hip_runtime.h>
#include <math.h>

#define HEADS1 4
#define HID 64
#define LSTM_H 32
#define IN_F 128
#define T_STEPS 50
#define NEG_SLOPE 0.2f
#define EPS_A 1e-16f
#define NPB 8   // LSTM nodes per block

// ---------- helpers ----------
__device__ __forceinline__ float sigf(float x) { return 1.0f / (1.0f + __expf(-x)); }
__device__ __forceinline__ float tanhfast(float x) {
    float e = __expf(2.0f * x);
    return 1.0f - 2.0f / (e + 1.0f);
}

// ---------- GEMM: C[M,NC] = A[M,K] @ B[K,NC]; 64x64 tile, 4x4 micro ----------
template <int K, int NC>
__global__ __launch_bounds__(256) void gemm64(const float* __restrict__ A,
                                              const float* __restrict__ B,
                                              float* __restrict__ C, int M) {
    constexpr int KC = 32;
    __shared__ float As[KC][68];   // [kk][row], pad 68 keeps float4 alignment, spreads banks
    __shared__ float Bs[KC][64];   // [kk][col]
    const int row0 = blockIdx.x * 64;
    const int col0 = blockIdx.y * 64;
    const int tx = threadIdx.x & 15;    // -> 4 cols
    const int ty = threadIdx.x >> 4;    // -> 4 rows
    float acc[4][4] = {{0.f}};

    for (int k0 = 0; k0 < K; k0 += KC) {
        // stage A (transposed): thread i -> kk = i&31, rows i>>5 + 8*r
        {
            const int kk = threadIdx.x & 31;
            const int rb = threadIdx.x >> 5;
#pragma unroll
            for (int r = 0; r < 8; r++) {
                int row = row0 + rb + r * 8;
                As[kk][rb + r * 8] = (row < M) ? A[(size_t)row * K + k0 + kk] : 0.0f;
            }
            const int c  = threadIdx.x & 63;
            const int kb = threadIdx.x >> 6;
#pragma unroll
            for (int q = 0; q < KC / 4; q++)
                Bs[kb + q * 4][c] = B[(size_t)(k0 + kb + q * 4) * NC + col0 + c];
        }
        __syncthreads();
#pragma unroll
        for (int kk = 0; kk < KC; kk++) {
            float4 a4 = *(const float4*)&As[kk][ty * 4];
            float4 b4 = *(const float4*)&Bs[kk][tx * 4];
            float av[4] = {a4.x, a4.y, a4.z, a4.w};
            float bv[4] = {b4.x, b4.y, b4.z, b4.w};
#pragma unroll
            for (int i = 0; i < 4; i++)
#pragma unroll
                for (int j = 0; j < 4; j++) acc[i][j] += av[i] * bv[j];
        }
        __syncthreads();
    }
#pragma unroll
    for (int i = 0; i < 4; i++) {
        int row = row0 + ty * 4 + i;
        if (row < M) {
            float4 v = make_float4(acc[i][0], acc[i][1], acc[i][2], acc[i][3]);
            *(float4*)&C[(size_t)row * NC + col0 + tx * 4] = v;
        }
    }
}

// ---------- attention scores ----------
__global__ void att_scores(const float* __restrict__ h, const float* __restrict__ att_s,
                           const float* __restrict__ att_d, float* __restrict__ as_,
                           float* __restrict__ ad_, int NH, int Hmask) {
    int i = blockIdx.x * blockDim.x + threadIdx.x;
    if (i >= NH) return;
    int hh = i & Hmask;
    const float* row = h + (size_t)i * HID;
    float s = 0.0f, d = 0.0f;
#pragma unroll 8
    for (int c = 0; c < HID; c++) {
        float v = row[c];
        s += v * att_s[hh * HID + c];
        d += v * att_d[hh * HID + c];
    }
    as_[i] = s;
    ad_[i] = d;
}

// ---------- CSR build ----------
__global__ void count_deg(const int* __restrict__ dsts, int E, int ET, int* __restrict__ cnt) {
    int e = blockIdx.x * blockDim.x + threadIdx.x;
    if (e >= ET) return;
    int d = (e < E) ? dsts[e] : (e - E);
    atomicAdd(&cnt[d], 1);
}

__global__ void scan1(const int* __restrict__ cnt, int* __restrict__ rowp,
                      int* __restrict__ bsum, int N) {
    __shared__ int tmp[256];
    int i = blockIdx.x * 256 + threadIdx.x;
    int v = (i < N) ? cnt[i] : 0;
    tmp[threadIdx.x] = v;
    __syncthreads();
    for (int off = 1; off < 256; off <<= 1) {
        int t = (threadIdx.x >= (unsigned)off) ? tmp[threadIdx.x - off] : 0;
        __syncthreads();
        tmp[threadIdx.x] += t;
        __syncthreads();
    }
    if (i < N) rowp[i] = tmp[threadIdx.x] - v;
    if (threadIdx.x == 255) bsum[blockIdx.x] = tmp[255];
}

__global__ void scan2(int* __restrict__ bsum, int nb) {   // one block, nb<=256
    __shared__ int tmp[256];
    int v = (threadIdx.x < (unsigned)nb) ? bsum[threadIdx.x] : 0;
    tmp[threadIdx.x] = v;
    __syncthreads();
    for (int off = 1; off < 256; off <<= 1) {
        int t = (threadIdx.x >= (unsigned)off) ? tmp[threadIdx.x - off] : 0;
        __syncthreads();
        tmp[threadIdx.x] += t;
        __syncthreads();
    }
    if (threadIdx.x < (unsigned)nb) bsum[threadIdx.x] = tmp[threadIdx.x] - v;
}

__global__ void scan3(int* __restrict__ rowp, const int* __restrict__ bsum, int N, int ET) {
    int i = blockIdx.x * 256 + threadIdx.x;
    if (i < N) rowp[i] += bsum[blockIdx.x];
    if (i == 0) rowp[N] = ET;
}

__global__ void scatter_edges(const int* __restrict__ dsts, int E, int ET,
                              const int* __restrict__ rowp, int* __restrict__ cursor,
                              int* __restrict__ eid) {
    int e = blockIdx.x * blockDim.x + threadIdx.x;
    if (e >= ET) return;
    int d = (e < E) ? dsts[e] : (e - E);
    int pos = atomicAdd(&cursor[d], 1);
    eid[rowp[d] + pos] = e;
}

// ---------- LSTM body: 256 threads = 8 nodes x 32 hidden units ----------
// Whh rows pinned in VGPRs via IN-LOOP asm: loop-carried asm dependency makes
// rematerialization / AGPR-shuttling impossible (round-3 VGPR=116 failure).
__device__ __forceinline__ void lstm_body(const float* __restrict__ seq,
                                          const float* __restrict__ Wih,
                                          const float* __restrict__ Whh,
                                          const float* __restrict__ bih,
                                          const float* __restrict__ bhh,
                                          float* __restrict__ t_out, int N, int bid) {
    __shared__ float s_seq[NPB * T_STEPS * 3];
    __shared__ float s_h[2][NPB][LSTM_H];

    const int local = threadIdx.x >> 5;
    const int j     = threadIdx.x & 31;
    const int node0 = bid * NPB;
    const int node  = node0 + local;

    {
        const float* src = seq + (size_t)node0 * (T_STEPS * 3);
        const int total = NPB * T_STEPS * 3;
        for (int i = threadIdx.x; i < total; i += 256) {
            int gn = node0 + i / (T_STEPS * 3);
            s_seq[i] = (gn < N) ? src[i] : 0.0f;
        }
    }

    float w[4][LSTM_H];
#pragma unroll
    for (int g = 0; g < 4; g++) {
        const float4* rp = (const float4*)(Whh + (size_t)(g * 32 + j) * 32);
#pragma unroll
        for (int q = 0; q < 8; q++) {
            float4 v = rp[q];
            w[g][q * 4 + 0] = v.x; w[g][q * 4 + 1] = v.y;
            w[g][q * 4 + 2] = v.z; w[g][q * 4 + 3] = v.w;
        }
    }
    float wi[4][3], bz[4];
#pragma unroll
    for (int g = 0; g < 4; g++) {
        int r = g * 32 + j;
        wi[g][0] = Wih[r * 3 + 0];
        wi[g][1] = Wih[r * 3 + 1];
        wi[g][2] = Wih[r * 3 + 2];
        bz[g] = bih[r] + bhh[r];
    }

    float c = 0.0f, hn = 0.0f;
    s_h[0][local][j] = 0.0f;
    __syncthreads();

#pragma unroll 1
    for (int t = 0; t < T_STEPS; t++) {
        // loop-carried VGPR pin: forces w resident across iterations
#pragma unroll
        for (int g = 0; g < 4; g++)
#pragma unroll
            for (int k = 0; k < LSTM_H; k++) asm volatile("" : "+v"(w[g][k]));

        const int cur = t & 1, nxt = cur ^ 1;
        float x0 = s_seq[local * 150 + t * 3 + 0];
        float x1 = s_seq[local * 150 + t * 3 + 1];
        float x2 = s_seq[local * 150 + t * 3 + 2];
        float z[4];
#pragma unroll
        for (int g = 0; g < 4; g++)
            z[g] = bz[g] + wi[g][0] * x0 + wi[g][1] * x1 + wi[g][2] * x2;
        const float4* hp = (const float4*)s_h[cur][local];
#pragma unroll
        for (int q = 0; q < 8; q++) {
            float4 hv = hp[q];
#pragma unroll
            for (int g = 0; g < 4; g++) {
                z[g] += w[g][q * 4 + 0] * hv.x + w[g][q * 4 + 1] * hv.y +
                        w[g][q * 4 + 2] * hv.z + w[g][q * 4 + 3] * hv.w;
            }
        }
        float ig = sigf(z[0]), fg = sigf(z[1]);
        float gg = tanhfast(z[2]), og = sigf(z[3]);
        c = fg * c + ig * gg;
        hn = og * tanhfast(c);
        __builtin_amdgcn_wave_barrier();
        s_h[nxt][local][j] = hn;
        __builtin_amdgcn_wave_barrier();
    }

    if (node < N) t_out[(size_t)node0 * LSTM_H + threadIdx.x] = hn;
}

// ---------- merged kernel: LSTM blocks first, then per-dst GAT aggregation ----------
// LSTM (ALU-bound) and the gather-heavy aggregation (memory-latency-bound)
// co-resident on each CU: gathers' stalls are filled with LSTM VALU work.
template <int H>
__global__ __launch_bounds__(256, 3)
void agg_lstm(const int* __restrict__ srcs, int E,
              const int* __restrict__ rowp, const int* __restrict__ eid,
              const float* __restrict__ as_, const float* __restrict__ ad_,
              const float* __restrict__ hfeat, const float* __restrict__ bias,
              float* __restrict__ g, int N, int do_elu,
              const float* __restrict__ seq, const float* __restrict__ Wih,
              const float* __restrict__ Whh, const float* __restrict__ bih,
              const float* __restrict__ bhh, float* __restrict__ t_out, int lstmBlocks) {
    if ((int)blockIdx.x < lstmBlocks) {
        lstm_body(seq, Wih, Whh, bih, bhh, t_out, N, blockIdx.x);
        return;
    }
    const int bid = blockIdx.x - lstmBlocks;
    const int wave = threadIdx.x >> 6;
    const int lane = threadIdx.x & 63;
    int dst, h;
    if (H == 4) { dst = bid; h = wave; }
    else        { dst = bid * 4 + wave; h = 0; }
    if (dst >= N) return;
    const int start = rowp[dst], end = rowp[dst + 1];
    const float adv = ad_[dst * H + h];

    float m = -INFINITY;
    for (int i0 = start; i0 < end; i0 += 64) {
        int i = i0 + lane;
        float v = -INFINITY;
        if (i < end) {
            int e = eid[i];
            int s = (e < E) ? srcs[e] : (e - E);
            float t = as_[s * H + h] + adv;
            v = (t > 0.0f) ? t : NEG_SLOPE * t;
        }
        m = fmaxf(m, v);
    }
#pragma unroll
    for (int mk = 32; mk >= 1; mk >>= 1) m = fmaxf(m, __shfl_xor(m, mk));

    float dsum = 0.0f;
    for (int i0 = start; i0 < end; i0 += 64) {
        int i = i0 + lane;
        float x = 0.0f;
        if (i < end) {
            int e = eid[i];
            int s = (e < E) ? srcs[e] : (e - E);
            float t = as_[s * H + h] + adv;
            t = (t > 0.0f) ? t : NEG_SLOPE * t;
            x = __expf(t - m);
        }
        dsum += x;
    }
#pragma unroll
    for (int mk = 32; mk >= 1; mk >>= 1) dsum += __shfl_xor(dsum, mk);
    const float inv = 1.0f / (dsum + EPS_A);

    float acc = 0.0f;
    for (int i0 = start; i0 < end; i0 += 64) {
        int cnt = min(64, end - i0);
        int i = i0 + lane;
        float alpha = 0.0f;
        int s = 0;
        if (i < end) {
            int e = eid[i];
            s = (e < E) ? srcs[e] : (e - E);
            float t = as_[s * H + h] + adv;
            t = (t > 0.0f) ? t : NEG_SLOPE * t;
            alpha = __expf(t - m) * inv;
        }
#pragma unroll 4
        for (int k = 0; k < cnt; k++) {
            float a_k = __shfl(alpha, k);
            int   s_k = __shfl(s, k);
            acc += hfeat[(size_t)s_k * (H * 64) + h * 64 + lane] * a_k;
        }
    }
    float r = acc + bias[h * 64 + lane];
    if (do_elu) r = (r > 0.0f) ? r : __expf(r) - 1.0f;
    g[(size_t)dst * (H * 64) + h * 64 + lane] = r;
}

// ---------- fusion MLP ----------
__global__ void fusion_kernel(const float* __restrict__ g2, const float* __restrict__ tt,
                              const float* __restrict__ Wf1, const float* __restrict__ bf1,
                              const float* __restrict__ Wf2, const float* __restrict__ bf2,
                              float* __restrict__ out, int N) {
    __shared__ float sW[96 * 64];
    __shared__ float sb1[64];
    __shared__ float sW2[128];
    for (int i = threadIdx.x; i < 96 * 64; i += 256) sW[i] = Wf1[i];
    if (threadIdx.x < 64) sb1[threadIdx.x] = bf1[threadIdx.x];
    if (threadIdx.x < 128) sW2[threadIdx.x] = Wf2[threadIdx.x];
    __syncthreads();
    const int wave = threadIdx.x >> 6;
    const int lane = threadIdx.x & 63;
    for (int n = blockIdx.x * 4 + wave; n < N; n += gridDim.x * 4) {
        const float* gn = g2 + (size_t)n * 64;
        const float* tn = tt + (size_t)n * 32;
        float acc = sb1[lane];
#pragma unroll 8
        for (int k = 0; k < 64; k++) acc += gn[k] * sW[k * 64 + lane];
#pragma unroll 8
        for (int k = 0; k < 32; k++) acc += tn[k] * sW[(64 + k) * 64 + lane];
        acc = fmaxf(acc, 0.0f);
        float o0 = acc * sW2[lane * 2 + 0];
        float o1 = acc * sW2[lane * 2 + 1];
#pragma unroll
        for (int mk = 32; mk >= 1; mk >>= 1) {
            o0 += __shfl_xor(o0, mk);
            o1 += __shfl_xor(o1, mk);
        }
        if (lane == 0) {
            out[(size_t)n * 2 + 0] = o0 + bf2[0];
            out[(size_t)n * 2 + 1] = o1 + bf2[1];
        }
    }
}

extern "C" void kernel_launch(void* const* d_in, const int* in_sizes, int n_in,
                              void* d_out, int out_size, void* d_ws, size_t ws_size,
                              hipStream_t stream) {
    const float* x      = (const float*)d_in[0];
    const int*   eidx   = (const int*)d_in[1];
    const float* seq    = (const float*)d_in[2];
    const float* W1     = (const float*)d_in[3];
    const float* att_s1 = (const float*)d_in[4];
    const float* att_d1 = (const float*)d_in[5];
    const float* bias1  = (const float*)d_in[6];
    const float* W2     = (const float*)d_in[7];
    const float* att_s2 = (const float*)d_in[8];
    const float* att_d2 = (const float*)d_in[9];
    const float* bias2  = (const float*)d_in[10];
    const float* Wih    = (const float*)d_in[11];
    const float* Whh    = (const float*)d_in[12];
    const float* bih    = (const float*)d_in[13];
    const float* bhh    = (const float*)d_in[14];
    const float* Wf1    = (const float*)d_in[15];
    const float* bf1    = (const float*)d_in[16];
    const float* Wf2    = (const float*)d_in[17];
    const float* bf2    = (const float*)d_in[18];
    float* out = (float*)d_out;

    const int N  = in_sizes[0] / IN_F;   // 50000
    const int E  = in_sizes[1] / 2;      // 800000
    const int ET = E + N;
    const int* srcs = eidx;
    const int* dsts = eidx + E;

    // workspace layout
    float* fws = (float*)d_ws;
    size_t o = 0;
    float* h1  = fws + o; o += (size_t)N * 256;
    float* g1  = fws + o; o += (size_t)N * 256;
    float* as1 = fws + o; o += (size_t)N * 4;
    float* ad1 = fws + o; o += (size_t)N * 4;
    int* cnt    = (int*)(fws + o);
    int* rowp   = cnt + N;
    int* cursor = rowp + N + 1;
    int* eid    = cursor + N;
    int* bsum   = eid + ET;            // 256 ints for the tile scan
    char* base_end = (char*)(bsum + 256);
    size_t need_tt = (size_t)N * LSTM_H * sizeof(float);
    bool bigws = ((size_t)(base_end - (char*)d_ws) + need_tt) <= ws_size;
    // bigws: tt dedicated -> LSTM can overlap layer-1 aggregation (which reads all of h1)
    // smallws: tt aliases h1+N*128 -> LSTM overlaps layer-2 aggregation (no alias conflict)
    float* tt = bigws ? (float*)base_end : (h1 + (size_t)N * 128);
    float* h2 = h1;                      // N*64, after layer-1 agg h1 is dead
    float* g2 = h1 + (size_t)N * 64;     // N*64
    float* as2 = as1; float* ad2 = ad1;

    const int lstmBlocks = (N + NPB - 1) / NPB;
    const int nTiles = (N + 255) / 256;
    dim3 blk(256);

    // ---- CSR build ----
    hipMemsetAsync(cnt, 0, (size_t)N * sizeof(int), stream);
    hipMemsetAsync(cursor, 0, (size_t)N * sizeof(int), stream);
    count_deg<<<(ET + 255) / 256, blk, 0, stream>>>(dsts, E, ET, cnt);
    scan1<<<nTiles, blk, 0, stream>>>(cnt, rowp, bsum, N);
    scan2<<<1, blk, 0, stream>>>(bsum, nTiles);
    scan3<<<(N + 256) / 256, blk, 0, stream>>>(rowp, bsum, N, ET);
    scatter_edges<<<(ET + 255) / 256, blk, 0, stream>>>(dsts, E, ET, rowp, cursor, eid);

    // ---- GAT layer 1 ----
    gemm64<128, 256><<<dim3((N + 63) / 64, 4), blk, 0, stream>>>(x, W1, h1, N);
    att_scores<<<(N * 4 + 255) / 256, blk, 0, stream>>>(h1, att_s1, att_d1, as1, ad1, N * 4, 3);
    if (bigws) {
        agg_lstm<4><<<lstmBlocks + N, blk, 0, stream>>>(
            srcs, E, rowp, eid, as1, ad1, h1, bias1, g1, N, 1,
            seq, Wih, Whh, bih, bhh, tt, lstmBlocks);
    } else {
        agg_lstm<4><<<N, blk, 0, stream>>>(
            srcs, E, rowp, eid, as1, ad1, h1, bias1, g1, N, 1,
            seq, Wih, Whh, bih, bhh, tt, 0);
    }

    // ---- GAT layer 2 ----
    gemm64<256, 64><<<dim3((N + 63) / 64, 1), blk, 0, stream>>>(g1, W2, h2, N);
    att_scores<<<(N + 255) / 256, blk, 0, stream>>>(h2, att_s2, att_d2, as2, ad2, N, 0);
    if (bigws) {
        agg_lstm<1><<<(N + 3) / 4, blk, 0, stream>>>(
            srcs, E, rowp, eid, as2, ad2, h2, bias2, g2, N, 0,
            seq, Wih, Whh, bih, bhh, tt, 0);
    } else {
        agg_lstm<1><<<lstmBlocks + (N + 3) / 4, blk, 0, stream>>>(
            srcs, E, rowp, eid, as2, ad2, h2, bias2, g2, N, 0,
            seq, Wih, Whh, bih, bhh, tt, lstmBlocks);
    }

    // ---- fusion MLP ----
    fusion_kernel<<<512, blk, 0, stream>>>(g2, tt, Wf1, bf1, Wf2, bf2, out, N);
}

// Round 5
// 1256.063 us; speedup vs baseline: 1.4058x; 1.4058x over previous
//
#include <hip/hip_runtime.h>
#include <math.h>

#define HEADS1 4
#define HID 64
#define LSTM_H 32
#define IN_F 128
#define T_STEPS 50
#define NEG_SLOPE 0.2f
#define EPS_A 1e-16f

// ---------- helpers ----------
__device__ __forceinline__ float sigf(float x) { return 1.0f / (1.0f + __expf(-x)); }
__device__ __forceinline__ float tanhfast(float x) {
    float e = __expf(2.0f * x);
    return 1.0f - 2.0f / (e + 1.0f);
}

// ---------- GEMM: C[M,NC] = A[M,K] @ B[K,NC]; 64x64 tile, 4x4 micro ----------
template <int K, int NC>
__global__ __launch_bounds__(256) void gemm64(const float* __restrict__ A,
                                              const float* __restrict__ B,
                                              float* __restrict__ C, int M) {
    constexpr int KC = 32;
    __shared__ float As[KC][68];
    __shared__ float Bs[KC][64];
    const int row0 = blockIdx.x * 64;
    const int col0 = blockIdx.y * 64;
    const int tx = threadIdx.x & 15;
    const int ty = threadIdx.x >> 4;
    float acc[4][4] = {{0.f}};

    for (int k0 = 0; k0 < K; k0 += KC) {
        {
            const int kk = threadIdx.x & 31;
            const int rb = threadIdx.x >> 5;
#pragma unroll
            for (int r = 0; r < 8; r++) {
                int row = row0 + rb + r * 8;
                As[kk][rb + r * 8] = (row < M) ? A[(size_t)row * K + k0 + kk] : 0.0f;
            }
            const int c  = threadIdx.x & 63;
            const int kb = threadIdx.x >> 6;
#pragma unroll
            for (int q = 0; q < KC / 4; q++)
                Bs[kb + q * 4][c] = B[(size_t)(k0 + kb + q * 4) * NC + col0 + c];
        }
        __syncthreads();
#pragma unroll
        for (int kk = 0; kk < KC; kk++) {
            float4 a4 = *(const float4*)&As[kk][ty * 4];
            float4 b4 = *(const float4*)&Bs[kk][tx * 4];
            float av[4] = {a4.x, a4.y, a4.z, a4.w};
            float bv[4] = {b4.x, b4.y, b4.z, b4.w};
#pragma unroll
            for (int i = 0; i < 4; i++)
#pragma unroll
                for (int j = 0; j < 4; j++) acc[i][j] += av[i] * bv[j];
        }
        __syncthreads();
    }
#pragma unroll
    for (int i = 0; i < 4; i++) {
        int row = row0 + ty * 4 + i;
        if (row < M) {
            float4 v = make_float4(acc[i][0], acc[i][1], acc[i][2], acc[i][3]);
            *(float4*)&C[(size_t)row * NC + col0 + tx * 4] = v;
        }
    }
}

// ---------- attention scores ----------
__global__ void att_scores(const float* __restrict__ h, const float* __restrict__ att_s,
                           const float* __restrict__ att_d, float* __restrict__ as_,
                           float* __restrict__ ad_, int NH, int Hmask) {
    int i = blockIdx.x * blockDim.x + threadIdx.x;
    if (i >= NH) return;
    int hh = i & Hmask;
    const float* row = h + (size_t)i * HID;
    float s = 0.0f, d = 0.0f;
#pragma unroll 8
    for (int c = 0; c < HID; c++) {
        float v = row[c];
        s += v * att_s[hh * HID + c];
        d += v * att_d[hh * HID + c];
    }
    as_[i] = s;
    ad_[i] = d;
}

// ---------- CSR build ----------
__global__ void count_deg(const int* __restrict__ dsts, int E, int ET, int* __restrict__ cnt) {
    int e = blockIdx.x * blockDim.x + threadIdx.x;
    if (e >= ET) return;
    int d = (e < E) ? dsts[e] : (e - E);
    atomicAdd(&cnt[d], 1);
}

__global__ void scan1(const int* __restrict__ cnt, int* __restrict__ rowp,
                      int* __restrict__ bsum, int N) {
    __shared__ int tmp[256];
    int i = blockIdx.x * 256 + threadIdx.x;
    int v = (i < N) ? cnt[i] : 0;
    tmp[threadIdx.x] = v;
    __syncthreads();
    for (int off = 1; off < 256; off <<= 1) {
        int t = (threadIdx.x >= (unsigned)off) ? tmp[threadIdx.x - off] : 0;
        __syncthreads();
        tmp[threadIdx.x] += t;
        __syncthreads();
    }
    if (i < N) rowp[i] = tmp[threadIdx.x] - v;
    if (threadIdx.x == 255) bsum[blockIdx.x] = tmp[255];
}

__global__ void scan2(int* __restrict__ bsum, int nb) {
    __shared__ int tmp[256];
    int v = (threadIdx.x < (unsigned)nb) ? bsum[threadIdx.x] : 0;
    tmp[threadIdx.x] = v;
    __syncthreads();
    for (int off = 1; off < 256; off <<= 1) {
        int t = (threadIdx.x >= (unsigned)off) ? tmp[threadIdx.x - off] : 0;
        __syncthreads();
        tmp[threadIdx.x] += t;
        __syncthreads();
    }
    if (threadIdx.x < (unsigned)nb) bsum[threadIdx.x] = tmp[threadIdx.x] - v;
}

__global__ void scan3(int* __restrict__ rowp, const int* __restrict__ bsum, int N, int ET) {
    int i = blockIdx.x * 256 + threadIdx.x;
    if (i < N) rowp[i] += bsum[blockIdx.x];
    if (i == 0) rowp[N] = ET;
}

__global__ void scatter_edges(const int* __restrict__ dsts, int E, int ET,
                              const int* __restrict__ rowp, int* __restrict__ cursor,
                              int* __restrict__ eid) {
    int e = blockIdx.x * blockDim.x + threadIdx.x;
    if (e >= ET) return;
    int d = (e < E) ? dsts[e] : (e - E);
    int pos = atomicAdd(&cursor[d], 1);
    eid[rowp[d] + pos] = e;
}

// ---------- fused per-dst GAT softmax + aggregation (standalone, round-3) ----------
template <int H>
__global__ void gat_agg_fused(const int* __restrict__ srcs, int E,
                              const int* __restrict__ rowp, const int* __restrict__ eid,
                              const float* __restrict__ as_, const float* __restrict__ ad_,
                              const float* __restrict__ hfeat, const float* __restrict__ bias,
                              float* __restrict__ g, int N, int do_elu) {
    const int wave = threadIdx.x >> 6;
    const int lane = threadIdx.x & 63;
    int dst, h;
    if (H == 4) { dst = blockIdx.x; h = wave; }
    else        { dst = blockIdx.x * 4 + wave; h = 0; }
    if (dst >= N) return;
    const int start = rowp[dst], end = rowp[dst + 1];
    const float adv = ad_[dst * H + h];

    float m = -INFINITY;
    for (int i0 = start; i0 < end; i0 += 64) {
        int i = i0 + lane;
        float v = -INFINITY;
        if (i < end) {
            int e = eid[i];
            int s = (e < E) ? srcs[e] : (e - E);
            float t = as_[s * H + h] + adv;
            v = (t > 0.0f) ? t : NEG_SLOPE * t;
        }
        m = fmaxf(m, v);
    }
#pragma unroll
    for (int mk = 32; mk >= 1; mk >>= 1) m = fmaxf(m, __shfl_xor(m, mk));

    float dsum = 0.0f;
    for (int i0 = start; i0 < end; i0 += 64) {
        int i = i0 + lane;
        float x = 0.0f;
        if (i < end) {
            int e = eid[i];
            int s = (e < E) ? srcs[e] : (e - E);
            float t = as_[s * H + h] + adv;
            t = (t > 0.0f) ? t : NEG_SLOPE * t;
            x = __expf(t - m);
        }
        dsum += x;
    }
#pragma unroll
    for (int mk = 32; mk >= 1; mk >>= 1) dsum += __shfl_xor(dsum, mk);
    const float inv = 1.0f / (dsum + EPS_A);

    float acc = 0.0f;
    for (int i0 = start; i0 < end; i0 += 64) {
        int cnt = min(64, end - i0);
        int i = i0 + lane;
        float alpha = 0.0f;
        int s = 0;
        if (i < end) {
            int e = eid[i];
            s = (e < E) ? srcs[e] : (e - E);
            float t = as_[s * H + h] + adv;
            t = (t > 0.0f) ? t : NEG_SLOPE * t;
            alpha = __expf(t - m) * inv;
        }
#pragma unroll 4
        for (int k = 0; k < cnt; k++) {
            float a_k = __shfl(alpha, k);
            int   s_k = __shfl(s, k);
            acc += hfeat[(size_t)s_k * (H * 64) + h * 64 + lane] * a_k;
        }
    }
    float r = acc + bias[h * 64 + lane];
    if (do_elu) r = (r > 0.0f) ? r : __expf(r) - 1.0f;
    g[(size_t)dst * (H * 64) + h * 64 + lane] = r;
}

// ---------- LSTM v4: one node per WAVE; lane = (half, j) ----------
// half 0 owns gate rows {i,f} of unit j; half 1 owns {g,o}. 64 Whh weights per
// thread (fits 4 waves/EU at <128 VGPR -> no spill pressure, unlike the 128-w
// layouts of rounds 2-4). Gate exchange via shfl_xor(32); no __syncthreads.
#define PIN8(a,b,c,d,e,f,g,h) asm volatile("" : "+v"(a),"+v"(b),"+v"(c),"+v"(d),"+v"(e),"+v"(f),"+v"(g),"+v"(h))
__global__ __launch_bounds__(256, 4)
void lstm_kernel(const float* __restrict__ seq, const float* __restrict__ Wih,
                 const float* __restrict__ Whh, const float* __restrict__ bih,
                 const float* __restrict__ bhh, float* __restrict__ t_out, int N) {
    __shared__ float s_seq[4][T_STEPS * 3];
    __shared__ float s_h[4][LSTM_H];

    const int wave = threadIdx.x >> 6;
    const int lane = threadIdx.x & 63;
    const int j    = lane & 31;
    const int half = lane >> 5;
    const int node = blockIdx.x * 4 + wave;
    if (node >= N) return;

    for (int i = lane; i < T_STEPS * 3; i += 64)
        s_seq[wave][i] = seq[(size_t)node * (T_STEPS * 3) + i];

    // rows: half*64 + {0,32} + j   (gate order i,f,g,o)
    float w[2][LSTM_H];
    float wi[2][3], bz[2];
#pragma unroll
    for (int gi = 0; gi < 2; gi++) {
        const int r = half * 64 + gi * 32 + j;
        const float4* rp = (const float4*)(Whh + (size_t)r * 32);
#pragma unroll
        for (int q = 0; q < 8; q++) {
            float4 v = rp[q];
            w[gi][q * 4 + 0] = v.x; w[gi][q * 4 + 1] = v.y;
            w[gi][q * 4 + 2] = v.z; w[gi][q * 4 + 3] = v.w;
        }
        wi[gi][0] = Wih[r * 3 + 0];
        wi[gi][1] = Wih[r * 3 + 1];
        wi[gi][2] = Wih[r * 3 + 2];
        bz[gi] = bih[r] + bhh[r];
    }
    // opaque grouped pins: weight defs become asm outputs -> cannot be
    // rematerialized from memory inside the loop (rounds 2-4 failure modes)
#pragma unroll
    for (int gi = 0; gi < 2; gi++) {
        PIN8(w[gi][0], w[gi][1], w[gi][2], w[gi][3], w[gi][4], w[gi][5], w[gi][6], w[gi][7]);
        PIN8(w[gi][8], w[gi][9], w[gi][10], w[gi][11], w[gi][12], w[gi][13], w[gi][14], w[gi][15]);
        PIN8(w[gi][16], w[gi][17], w[gi][18], w[gi][19], w[gi][20], w[gi][21], w[gi][22], w[gi][23]);
        PIN8(w[gi][24], w[gi][25], w[gi][26], w[gi][27], w[gi][28], w[gi][29], w[gi][30], w[gi][31]);
    }
    PIN8(wi[0][0], wi[0][1], wi[0][2], wi[1][0], wi[1][1], wi[1][2], bz[0], bz[1]);

    if (half == 0) s_h[wave][j] = 0.0f;
    float c = 0.0f;
    __builtin_amdgcn_wave_barrier();

#pragma unroll 1
    for (int t = 0; t < T_STEPS; t++) {
        float x0 = s_seq[wave][t * 3 + 0];
        float x1 = s_seq[wave][t * 3 + 1];
        float x2 = s_seq[wave][t * 3 + 2];
        float z0 = bz[0] + wi[0][0] * x0 + wi[0][1] * x1 + wi[0][2] * x2;
        float z1 = bz[1] + wi[1][0] * x0 + wi[1][1] * x1 + wi[1][2] * x2;
        const float4* hp = (const float4*)s_h[wave];
#pragma unroll
        for (int q = 0; q < 8; q++) {
            float4 hv = hp[q];
            z0 += w[0][q * 4 + 0] * hv.x + w[0][q * 4 + 1] * hv.y +
                  w[0][q * 4 + 2] * hv.z + w[0][q * 4 + 3] * hv.w;
            z1 += w[1][q * 4 + 0] * hv.x + w[1][q * 4 + 1] * hv.y +
                  w[1][q * 4 + 2] * hv.z + w[1][q * 4 + 3] * hv.w;
        }
        // half0: z0=zi, z1=zf ; half1: z0=zg, z1=zo
        // unified transcendental: sig(z0) [half0] vs tanh(z0) [half1], one exp+rcp
        float e0 = __expf(half ? 2.0f * z0 : -z0);
        float r0 = 1.0f / (e0 + 1.0f);
        float p0 = half ? (1.0f - 2.0f * r0) : r0;   // half0: ig ; half1: gg
        float p1 = sigf(z1);                          // half0: fg ; half1: og
        float q0 = __shfl_xor(p0, 32);                // half0 receives gg
        c = p1 * c + p0 * q0;                         // half0: fg*c + ig*gg (half1 garbage, bounded)
        float tc = tanhfast(c);                       // half0: tanh(c)
        float tcx = __shfl_xor(tc, 32);               // half1 receives tanh(c)
        float hn = p1 * tcx;                          // half1: og*tanh(c)
        __builtin_amdgcn_wave_barrier();
        if (half == 1) s_h[wave][j] = hn;
        __builtin_amdgcn_wave_barrier();
    }

    if (half == 1) {
        float hv = s_h[wave][j];
        t_out[(size_t)node * LSTM_H + j] = hv;
    }
}

// ---------- fusion MLP ----------
__global__ void fusion_kernel(const float* __restrict__ g2, const float* __restrict__ tt,
                              const float* __restrict__ Wf1, const float* __restrict__ bf1,
                              const float* __restrict__ Wf2, const float* __restrict__ bf2,
                              float* __restrict__ out, int N) {
    __shared__ float sW[96 * 64];
    __shared__ float sb1[64];
    __shared__ float sW2[128];
    for (int i = threadIdx.x; i < 96 * 64; i += 256) sW[i] = Wf1[i];
    if (threadIdx.x < 64) sb1[threadIdx.x] = bf1[threadIdx.x];
    if (threadIdx.x < 128) sW2[threadIdx.x] = Wf2[threadIdx.x];
    __syncthreads();
    const int wave = threadIdx.x >> 6;
    const int lane = threadIdx.x & 63;
    for (int n = blockIdx.x * 4 + wave; n < N; n += gridDim.x * 4) {
        const float* gn = g2 + (size_t)n * 64;
        const float* tn = tt + (size_t)n * 32;
        float acc = sb1[lane];
#pragma unroll 8
        for (int k = 0; k < 64; k++) acc += gn[k] * sW[k * 64 + lane];
#pragma unroll 8
        for (int k = 0; k < 32; k++) acc += tn[k] * sW[(64 + k) * 64 + lane];
        acc = fmaxf(acc, 0.0f);
        float o0 = acc * sW2[lane * 2 + 0];
        float o1 = acc * sW2[lane * 2 + 1];
#pragma unroll
        for (int mk = 32; mk >= 1; mk >>= 1) {
            o0 += __shfl_xor(o0, mk);
            o1 += __shfl_xor(o1, mk);
        }
        if (lane == 0) {
            out[(size_t)n * 2 + 0] = o0 + bf2[0];
            out[(size_t)n * 2 + 1] = o1 + bf2[1];
        }
    }
}

extern "C" void kernel_launch(void* const* d_in, const int* in_sizes, int n_in,
                              void* d_out, int out_size, void* d_ws, size_t ws_size,
                              hipStream_t stream) {
    const float* x      = (const float*)d_in[0];
    const int*   eidx   = (const int*)d_in[1];
    const float* seq    = (const float*)d_in[2];
    const float* W1     = (const float*)d_in[3];
    const float* att_s1 = (const float*)d_in[4];
    const float* att_d1 = (const float*)d_in[5];
    const float* bias1  = (const float*)d_in[6];
    const float* W2     = (const float*)d_in[7];
    const float* att_s2 = (const float*)d_in[8];
    const float* att_d2 = (const float*)d_in[9];
    const float* bias2  = (const float*)d_in[10];
    const float* Wih    = (const float*)d_in[11];
    const float* Whh    = (const float*)d_in[12];
    const float* bih    = (const float*)d_in[13];
    const float* bhh    = (const float*)d_in[14];
    const float* Wf1    = (const float*)d_in[15];
    const float* bf1    = (const float*)d_in[16];
    const float* Wf2    = (const float*)d_in[17];
    const float* bf2    = (const float*)d_in[18];
    float* out = (float*)d_out;

    const int N  = in_sizes[0] / IN_F;   // 50000
    const int E  = in_sizes[1] / 2;      // 800000
    const int ET = E + N;
    const int* srcs = eidx;
    const int* dsts = eidx + E;

    // workspace layout
    float* fws = (float*)d_ws;
    size_t o = 0;
    float* h1  = fws + o; o += (size_t)N * 256;
    float* g1  = fws + o; o += (size_t)N * 256;
    float* as1 = fws + o; o += (size_t)N * 4;
    float* ad1 = fws + o; o += (size_t)N * 4;
    int* cnt    = (int*)(fws + o);
    int* rowp   = cnt + N;
    int* cursor = rowp + N + 1;
    int* eid    = cursor + N;
    int* bsum   = eid + ET;
    // layer-2 / LSTM aliases (h1 region dead after layer-1 aggregation)
    float* h2 = h1;                      // N*64
    float* g2 = h1 + (size_t)N * 64;     // N*64
    float* tt = h1 + (size_t)N * 128;    // N*32
    float* as2 = as1; float* ad2 = ad1;

    const int nTiles = (N + 255) / 256;
    dim3 blk(256);

    // ---- CSR build ----
    hipMemsetAsync(cnt, 0, (size_t)N * sizeof(int), stream);
    hipMemsetAsync(cursor, 0, (size_t)N * sizeof(int), stream);
    count_deg<<<(ET + 255) / 256, blk, 0, stream>>>(dsts, E, ET, cnt);
    scan1<<<nTiles, blk, 0, stream>>>(cnt, rowp, bsum, N);
    scan2<<<1, blk, 0, stream>>>(bsum, nTiles);
    scan3<<<(N + 256) / 256, blk, 0, stream>>>(rowp, bsum, N, ET);
    scatter_edges<<<(ET + 255) / 256, blk, 0, stream>>>(dsts, E, ET, rowp, cursor, eid);

    // ---- GAT layer 1 ----
    gemm64<128, 256><<<dim3((N + 63) / 64, 4), blk, 0, stream>>>(x, W1, h1, N);
    att_scores<<<(N * 4 + 255) / 256, blk, 0, stream>>>(h1, att_s1, att_d1, as1, ad1, N * 4, 3);
    gat_agg_fused<4><<<N, blk, 0, stream>>>(srcs, E, rowp, eid, as1, ad1, h1, bias1, g1, N, 1);

    // ---- LSTM (independent; tt region is free once layer-1 agg is done) ----
    lstm_kernel<<<(N + 3) / 4, blk, 0, stream>>>(seq, Wih, Whh, bih, bhh, tt, N);

    // ---- GAT layer 2 ----
    gemm64<256, 64><<<dim3((N + 63) / 64, 1), blk, 0, stream>>>(g1, W2, h2, N);
    att_scores<<<(N + 255) / 256, blk, 0, stream>>>(h2, att_s2, att_d2, as2, ad2, N, 0);
    gat_agg_fused<1><<<(N + 3) / 4, blk, 0, stream>>>(srcs, E, rowp, eid, as2, ad2, h2, bias2, g2, N, 0);

    // ---- fusion MLP ----
    fusion_kernel<<<512, blk, 0, stream>>>(g2, tt, Wf1, bf1, Wf2, bf2, out, N);
}